// Round 18
// baseline (104.578 us; speedup 1.0000x reference)
//
#include <hip/hip_runtime.h>

#define CI 32
#define CO 32
#define PD 64
#define QDIM 1024
#define M_TOTAL (32*4096)
#define TILE_M 128                 // per WG: waves = (rg 0..1) x (ih 0..1)
#define NBLK (M_TOTAL/TILE_M)      // 1024 WGs; supply 16 waves/CU = 4/SIMD
#define WG_THREADS 256
#define OLS 33                     // U.o[lane][r]: 2-way free

typedef float  f32x4  __attribute__((ext_vector_type(4)));
typedef float  f32x16 __attribute__((ext_vector_type(16)));
typedef __bf16 bf16x4 __attribute__((ext_vector_type(4)));
typedef __bf16 bf16x8 __attribute__((ext_vector_type(8)));

// ---- one-time: Wk [64][1024] f32 -> wsF, MFMA-A-fragment-linear layout ----
// wsF idx = (q>>5)*2048 + (k>>3)*256 + (q&31)*8 + (k&7); per i, frag f, lane
// (l31,hi) reads contiguous: wsF + i*2048 + (2f+hi)*256 + l31*8
__global__ __launch_bounds__(256)
void wk_pack_kernel(const float* __restrict__ Wk, __bf16* __restrict__ wsF)
{
    __shared__ float tile[64][33];
    const int q0 = blockIdx.x * 32;
    const int t  = threadIdx.x;
#pragma unroll
    for (int s = 0; s < 2; ++s) {
        const int idx = t + s * 256;
        const int k = idx >> 3, ch = idx & 7;
        f32x4 v = *(const f32x4*)(Wk + (size_t)k * QDIM + q0 + ch * 4);
        tile[k][ch*4+0] = v[0]; tile[k][ch*4+1] = v[1];
        tile[k][ch*4+2] = v[2]; tile[k][ch*4+3] = v[3];
    }
    __syncthreads();
    const int qq = t >> 3;
    const int g  = t & 7;
    bf16x8 o;
#pragma unroll
    for (int j = 0; j < 8; ++j) o[j] = (__bf16)tile[g*8 + j][qq];
    *(bf16x8*)(wsF + (size_t)blockIdx.x * 2048 + g * 256 + qq * 8) = o;
}

// R17 skeleton (i-split, 16 waves/CU supply, launch_bounds(256,2)) with the
// X path moved OUT of LDS: each lane reads its own X[m, 16-i-half] as f32x4
// groups straight from global (one full 64B sector per row-half; L1-hit after
// first touch). Kills the per-step ds_read dependency in the epilogue (ds
// latency ~120cy, single-outstanding) and drops LDS to 16.9 KB.
__global__ __launch_bounds__(WG_THREADS, 2)
void cond_dense_kernel(const float* __restrict__ Xg, const float* __restrict__ Pg,
                       const __bf16* __restrict__ wsF, float* __restrict__ outg)
{
    __shared__ union {
        __bf16 p[TILE_M * PD];       // 16384 B: P-tile (dead after bfrag)
        float  o[2 * 64 * OLS];      // 16896 B: partial-sum exchange
    } U;

    const int t   = threadIdx.x;
    const int l   = t & 63;
    const int w   = t >> 6;
    const int rg  = w & 1;          // row-group: rows rg*64 .. rg*64+63
    const int ih  = w >> 1;         // i-half: i in ih*16 .. ih*16+15
    const int l31 = l & 31;
    const int hi  = l >> 5;
    const int tile0 = blockIdx.x * TILE_M;
    const int m0  = rg * 64 + l31;  // lane's first row (second = m0+32)

    // ---- stage: P[128][64] -> bf16 swizzled LDS (X no longer staged) ----
    {
        const float* Pb = Pg + (size_t)tile0 * PD;
#pragma unroll
        for (int s = 0; s < 8; ++s) {
            const int id = t + 256 * s;
            const int r = id >> 4, ch = id & 15;
            f32x4 v = *(const f32x4*)(Pb + (size_t)r * PD + ch * 4);
            bf16x4 bv;
#pragma unroll
            for (int j = 0; j < 4; ++j) bv[j] = (__bf16)v[j];
            char* dst = (char*)U.p + r * 128
                      + ((((ch >> 1) ^ (r & 7)) << 4) | ((ch & 1) * 8));
            *(bf16x4*)dst = bv;
        }
    }
    __syncthreads();

    // ---- B fragments (P^T) for rows m0, m0+32 (m0&7 == l31&7) ----
    bf16x8 bfA[4], bfB[4];
#pragma unroll
    for (int kq = 0; kq < 4; ++kq) {
        const int g = ((kq * 2 + hi) ^ (l31 & 7)) << 4;
        bfA[kq] = *(const bf16x8*)((const char*)U.p + m0 * 128 + g);
        bfB[kq] = *(const bf16x8*)((const char*)U.p + (m0 + 32) * 128 + g);
    }

    // ---- i-loop over this wave's half: 16 steps in 4 groups of 4 ----
    f32x16 oA = {}, oB = {};
    const __bf16* abase = wsF + (size_t)(ih * 16) * 2048
                        + (size_t)hi * 256 + (size_t)l31 * 8;
    // per-lane X rows (global): 16 i's of this half = one 64B sector per row
    const float* xr0 = Xg + (size_t)(tile0 + m0) * CI + ih * 16;
    const float* xr1 = xr0 + 32 * CI;

    bf16x8 a0[4], a1[4];
    auto aload = [&](int i, bf16x8* buf) {   // i local 0..15
        const __bf16* ap = abase + (size_t)i * 2048;
        buf[0] = *(const bf16x8*)(ap);
        buf[1] = *(const bf16x8*)(ap +  512);
        buf[2] = *(const bf16x8*)(ap + 1024);
        buf[3] = *(const bf16x8*)(ap + 1536);
    };
    auto step = [&](const bf16x8* a, float xl, float xh) {
        f32x16 c0 = {}, c1 = {};
#pragma unroll
        for (int kq = 0; kq < 4; ++kq) {     // 2 independent chains
            c0 = __builtin_amdgcn_mfma_f32_32x32x16_bf16(a[kq], bfA[kq], c0, 0, 0, 0);
            c1 = __builtin_amdgcn_mfma_f32_32x32x16_bf16(a[kq], bfB[kq], c1, 0, 0, 0);
        }
#pragma unroll
        for (int r = 0; r < 16; ++r) {
            oA[r] += fmaxf(c0[r], 0.0f) * xl;
            oB[r] += fmaxf(c1[r], 0.0f) * xh;
        }
    };

    aload(0, a0);
    aload(1, a1);
#pragma unroll
    for (int g = 0; g < 4; ++g) {
        const f32x4 xv0 = *(const f32x4*)(xr0 + g * 4);   // x in regs: no LDS dep
        const f32x4 xv1 = *(const f32x4*)(xr1 + g * 4);
#pragma unroll
        for (int s = 0; s < 4; ++s) {
            const int i = g * 4 + s;
            if (i & 1) {
                step(a1, xv0[s], xv1[s]);
                if (i + 2 < 16) aload(i + 2, a1);
            } else {
                step(a0, xv0[s], xv1[s]);
                if (i + 2 < 16) aload(i + 2, a0);
            }
        }
    }

    // ---- combine partials: ih=1 publishes, ih=0 adds and stores ----
    __syncthreads();                       // bfrag reads done; U.p -> U.o
    if (ih == 1) {
        const int ob = (rg * 64 + l) * OLS;
#pragma unroll
        for (int r = 0; r < 16; ++r) {
            U.o[ob + r]      = oA[r];
            U.o[ob + 16 + r] = oB[r];
        }
    }
    __syncthreads();
    if (ih == 0) {
        const int ob = (rg * 64 + l) * OLS;
#pragma unroll
        for (int r = 0; r < 16; ++r) {
            oA[r] += U.o[ob + r];
            oB[r] += U.o[ob + 16 + r];
        }
        // direct stores: lane rows m0/m0+32, cols 4*hi+8*rq
        float* orow  = outg + (size_t)(tile0 + m0) * CO + 4 * hi;
        float* orow2 = orow + 32 * CO;
#pragma unroll
        for (int rq = 0; rq < 4; ++rq) {
            f32x4 vA, vB;
#pragma unroll
            for (int j = 0; j < 4; ++j) { vA[j] = oA[4*rq + j]; vB[j] = oB[4*rq + j]; }
            *(f32x4*)(orow  + 8 * rq) = vA;
            *(f32x4*)(orow2 + 8 * rq) = vB;
        }
    }
}

extern "C" void kernel_launch(void* const* d_in, const int* in_sizes, int n_in,
                              void* d_out, int out_size, void* d_ws, size_t ws_size,
                              hipStream_t stream)
{
    const float* X  = (const float*)d_in[0];
    const float* P  = (const float*)d_in[1];
    const float* Wk = (const float*)d_in[2];
    float* out  = (float*)d_out;
    __bf16* wsF = (__bf16*)d_ws;   // 1024*64*2 = 128 KB

    wk_pack_kernel<<<dim3(QDIM / 32), dim3(256), 0, stream>>>(Wk, wsF);
    cond_dense_kernel<<<dim3(NBLK), dim3(WG_THREADS), 0, stream>>>(X, P, wsF, out);
}

// Round 19
// 36.979 us; speedup vs baseline: 2.8281x; 2.8281x over previous
//
#include <hip/hip_runtime.h>

#define CI 32
#define CO 32
#define PD 64
#define QDIM 1024
#define M_TOTAL (32*4096)
#define TILE_M 128                 // per WG: waves = (rg 0..1) x (ih 0..1)
#define NBLK (M_TOTAL/TILE_M)      // 1024 WGs; supply 16 waves/CU = 4/SIMD
#define WG_THREADS 256
#define XLS 33                     // Xl[m][i]: reads (l31+i)%32 conflict-free
#define OLS 33                     // U.o[lane][r]: 2-way free

typedef float  f32x2  __attribute__((ext_vector_type(2)));
typedef float  f32x4  __attribute__((ext_vector_type(4)));
typedef float  f32x16 __attribute__((ext_vector_type(16)));
typedef __bf16 bf16x4 __attribute__((ext_vector_type(4)));
typedef __bf16 bf16x8 __attribute__((ext_vector_type(8)));

// ---- one-time: Wk [64][1024] f32 -> wsF, MFMA-A-fragment-linear layout ----
// wsF idx = (q>>5)*2048 + (k>>3)*256 + (q&31)*8 + (k&7); per i, frag f, lane
// (l31,hi) reads contiguous: wsF + i*2048 + (2f+hi)*256 + l31*8
__global__ __launch_bounds__(256)
void wk_pack_kernel(const float* __restrict__ Wk, __bf16* __restrict__ wsF)
{
    __shared__ float tile[64][33];
    const int q0 = blockIdx.x * 32;
    const int t  = threadIdx.x;
#pragma unroll
    for (int s = 0; s < 2; ++s) {
        const int idx = t + s * 256;
        const int k = idx >> 3, ch = idx & 7;
        f32x4 v = *(const f32x4*)(Wk + (size_t)k * QDIM + q0 + ch * 4);
        tile[k][ch*4+0] = v[0]; tile[k][ch*4+1] = v[1];
        tile[k][ch*4+2] = v[2]; tile[k][ch*4+3] = v[3];
    }
    __syncthreads();
    const int qq = t >> 3;
    const int g  = t & 7;
    bf16x8 o;
#pragma unroll
    for (int j = 0; j < 8; ++j) o[j] = (__bf16)tile[g*8 + j][qq];
    *(bf16x8*)(wsF + (size_t)blockIdx.x * 2048 + g * 256 + qq * 8) = o;
}

// R17 base (best: 36.7us) + PACKED-F32 epilogue.
// R15 diag: MfmaUtil 26% + VALUBusy 59% = 85% issue at 1 wave/SIMD -> the
// step body is ISSUE-bound; epilogue's 64 scalar VALU/step dominates issue.
// VOP3P (v_pk_max_f32 / v_pk_fma_f32) halves that: acc tuples are 16-aligned
// so {c[2r],c[2r+1]} is a free register pair.
// DO NOT: X from global per-lane (R18: scatter + spill, 104us).
// DO NOT: launch_bounds min-waves 4 (R16: VGPR=64 + spills).
__global__ __launch_bounds__(WG_THREADS, 2)
void cond_dense_kernel(const float* __restrict__ Xg, const float* __restrict__ Pg,
                       const __bf16* __restrict__ wsF, float* __restrict__ outg)
{
    __shared__ union {
        __bf16 p[TILE_M * PD];       // 16384 B: P-tile (dead after bfrag)
        float  o[2 * 64 * OLS];      // 16896 B: partial-sum exchange
    } U;
    __shared__ float Xl[TILE_M * XLS];   // 16896 B: X row-major [m][i]

    const int t   = threadIdx.x;
    const int l   = t & 63;
    const int w   = t >> 6;
    const int rg  = w & 1;          // row-group: rows rg*64 .. rg*64+63
    const int ih  = w >> 1;         // i-half: i in ih*16 .. ih*16+15
    const int l31 = l & 31;
    const int hi  = l >> 5;
    const int tile0 = blockIdx.x * TILE_M;
    const int m0  = rg * 64 + l31;  // lane's first row (second = m0+32)

    // ---- stage: P[128][64] -> bf16 swizzled; X[128][32] -> Xl[m][i] ----
    {
        const float* Pb = Pg + (size_t)tile0 * PD;
#pragma unroll
        for (int s = 0; s < 8; ++s) {
            const int id = t + 256 * s;
            const int r = id >> 4, ch = id & 15;
            f32x4 v = *(const f32x4*)(Pb + (size_t)r * PD + ch * 4);
            bf16x4 bv;
#pragma unroll
            for (int j = 0; j < 4; ++j) bv[j] = (__bf16)v[j];
            char* dst = (char*)U.p + r * 128
                      + ((((ch >> 1) ^ (r & 7)) << 4) | ((ch & 1) * 8));
            *(bf16x4*)dst = bv;
        }
        const float* Xb = Xg + (size_t)tile0 * CI;
#pragma unroll
        for (int s = 0; s < 4; ++s) {
            const int id = t + 256 * s;
            const int r = id >> 3, ch = id & 7;
            f32x4 v = *(const f32x4*)(Xb + (size_t)r * CI + ch * 4);
#pragma unroll
            for (int j = 0; j < 4; ++j) Xl[r * XLS + ch * 4 + j] = v[j];
        }
    }
    __syncthreads();

    // ---- B fragments (P^T) for rows m0, m0+32 (m0&7 == l31&7) ----
    bf16x8 bfA[4], bfB[4];
#pragma unroll
    for (int kq = 0; kq < 4; ++kq) {
        const int g = ((kq * 2 + hi) ^ (l31 & 7)) << 4;
        bfA[kq] = *(const bf16x8*)((const char*)U.p + m0 * 128 + g);
        bfB[kq] = *(const bf16x8*)((const char*)U.p + (m0 + 32) * 128 + g);
    }

    // ---- i-loop over this wave's half: 16 steps, 2-deep A prefetch ----
    f32x2 oA[8] = {}, oB[8] = {};   // packed accumulators
    const __bf16* abase = wsF + (size_t)(ih * 16) * 2048
                        + (size_t)hi * 256 + (size_t)l31 * 8;
    const float* xb0 = &Xl[m0 * XLS + ih * 16];          // imm-offset reads
    const float* xb1 = &Xl[(m0 + 32) * XLS + ih * 16];

    bf16x8 a0[4], a1[4];
    auto aload = [&](int i, bf16x8* buf) {   // i local 0..15
        const __bf16* ap = abase + (size_t)i * 2048;
        buf[0] = *(const bf16x8*)(ap);
        buf[1] = *(const bf16x8*)(ap +  512);
        buf[2] = *(const bf16x8*)(ap + 1024);
        buf[3] = *(const bf16x8*)(ap + 1536);
    };
    const f32x2 zero2 = {0.0f, 0.0f};
    auto step = [&](const bf16x8* a, int i) {
        const float xl = xb0[i];
        const float xh = xb1[i];
        f32x16 c0 = {}, c1 = {};
#pragma unroll
        for (int kq = 0; kq < 4; ++kq) {     // 2 independent chains
            c0 = __builtin_amdgcn_mfma_f32_32x32x16_bf16(a[kq], bfA[kq], c0, 0, 0, 0);
            c1 = __builtin_amdgcn_mfma_f32_32x32x16_bf16(a[kq], bfB[kq], c1, 0, 0, 0);
        }
        const f32x2 xl2 = {xl, xl}, xh2 = {xh, xh};
#pragma unroll
        for (int r = 0; r < 8; ++r) {        // VOP3P: pk_max + pk_fma
            f32x2 p0 = {c0[2*r], c0[2*r + 1]};
            f32x2 p1 = {c1[2*r], c1[2*r + 1]};
            oA[r] += __builtin_elementwise_max(p0, zero2) * xl2;
            oB[r] += __builtin_elementwise_max(p1, zero2) * xh2;
        }
    };

    aload(0, a0);
    aload(1, a1);
    for (int ii = 0; ii < 8; ++ii) {
        step(a0, 2 * ii);
        if (ii < 7) aload(2 * ii + 2, a0);
        step(a1, 2 * ii + 1);
        if (ii < 7) aload(2 * ii + 3, a1);
    }

    // ---- combine partials: ih=1 publishes, ih=0 adds and stores ----
    __syncthreads();                       // bfrag reads long done; U.p -> U.o
    if (ih == 1) {
        const int ob = (rg * 64 + l) * OLS;
#pragma unroll
        for (int r = 0; r < 8; ++r) {
            *(f32x2*)&U.o[ob + 2*r]      = oA[r];
            *(f32x2*)&U.o[ob + 16 + 2*r] = oB[r];
        }
    }
    __syncthreads();
    if (ih == 0) {
        const int ob = (rg * 64 + l) * OLS;
#pragma unroll
        for (int r = 0; r < 8; ++r) {
            oA[r] += *(const f32x2*)&U.o[ob + 2*r];
            oB[r] += *(const f32x2*)&U.o[ob + 16 + 2*r];
        }
        // direct stores: lane rows m0/m0+32, cols 4*hi+8*rq
        float* orow  = outg + (size_t)(tile0 + m0) * CO + 4 * hi;
        float* orow2 = orow + 32 * CO;
#pragma unroll
        for (int rq = 0; rq < 4; ++rq) {
            f32x4 vA, vB;
#pragma unroll
            for (int j = 0; j < 4; ++j) {
                vA[j] = oA[2*rq + (j >> 1)][j & 1];
                vB[j] = oB[2*rq + (j >> 1)][j & 1];
            }
            *(f32x4*)(orow  + 8 * rq) = vA;
            *(f32x4*)(orow2 + 8 * rq) = vB;
        }
    }
}

extern "C" void kernel_launch(void* const* d_in, const int* in_sizes, int n_in,
                              void* d_out, int out_size, void* d_ws, size_t ws_size,
                              hipStream_t stream)
{
    const float* X  = (const float*)d_in[0];
    const float* P  = (const float*)d_in[1];
    const float* Wk = (const float*)d_in[2];
    float* out  = (float*)d_out;
    __bf16* wsF = (__bf16*)d_ws;   // 1024*64*2 = 128 KB

    wk_pack_kernel<<<dim3(QDIM / 32), dim3(256), 0, stream>>>(Wk, wsF);
    cond_dense_kernel<<<dim3(NBLK), dim3(WG_THREADS), 0, stream>>>(X, P, wsF, out);
}